// Round 11
// baseline (602.831 us; speedup 1.0000x reference)
//
#include <hip/hip_runtime.h>
#include <hip/hip_bf16.h>

// C[m,n] = sum_{r,k} A[r][m][k] * B[r][n][k]
// Phase 1: merged convert A,B -> bf16 in d_ws (K contiguous: k' = r*1024+k).
// Phase 2: 256x256 GEMM, BK=32, 16x16x32 MFMA, 8 waves (2Mx4N), T2 swizzle,
//          64 KiB LDS double-buffer -> 2 blocks/CU (16 waves/CU) so that
//          cross-block TLP hides barrier/waitcnt stalls (r6-r10 lesson:
//          at 1 block/CU every sync point is exposed; LDS volume, barrier
//          count and VALU addressing were all refuted as the limiter).

#define M_TOT 8192
#define N_TOT 4096
#define LK    1024
#define NR    8
#define K_TOT (NR * LK)     // 8192
#define NT32  (K_TOT / 32)  // 256 K-tiles of 32

typedef float f32x4 __attribute__((ext_vector_type(4)));
typedef short s16x8 __attribute__((ext_vector_type(8)));
typedef const __attribute__((address_space(1))) unsigned int* gptr_t;
typedef __attribute__((address_space(3))) unsigned int* lptr_t;

__device__ inline short f2bf(float f) {
    __hip_bfloat16 h = __float2bfloat16(f);
    return *reinterpret_cast<short*>(&h);
}

// ---------------- merged convert pre-pass ----------------
__global__ __launch_bounds__(256)
void cvt_all(const float* __restrict__ A, const float* __restrict__ B,
             short* __restrict__ Abf, short* __restrict__ Bbf) {
    int bid = blockIdx.x;
    const float* in;
    short* out;
    int row_shift, row_mask;
    if (bid < 32768) { in = A; out = Abf; row_shift = 13; row_mask = 8191; }
    else { bid -= 32768; in = B; out = Bbf; row_shift = 12; row_mask = 4095; }
    const int row = bid * 2 + (threadIdx.x >> 7);
    const int c   = (threadIdx.x & 127) * 8;
    const int r   = row >> row_shift;
    const int m   = row & row_mask;
    const float* src = in + ((size_t)row << 10) + c;
    f32x4 v0 = *(const f32x4*)src;
    f32x4 v1 = *(const f32x4*)(src + 4);
    s16x8 o;
    #pragma unroll
    for (int j = 0; j < 4; ++j) { o[j] = f2bf(v0[j]); o[j + 4] = f2bf(v1[j]); }
    *(s16x8*)(out + ((size_t)m << 13) + ((size_t)r << 10) + c) = o;
}

// ---------------- GEMM ----------------
// LDS (shorts): buf p at p*16384; A[256][32] at +0, B[256][32] at +8192.
// Row = 32 shorts = 4 granules of 16B. Swizzle: LDS granule g of row r
// holds global granule g ^ (r&3).

// stage one full A- or B-tile quadrant pair: 2 instrs (rows wid*16+... and +128)
__device__ __forceinline__ void stage2(const short* g, short* l) {
    #pragma unroll
    for (int q = 0; q < 2; ++q)
        __builtin_amdgcn_global_load_lds((gptr_t)(g + (size_t)q * 128 * K_TOT),
                                         (lptr_t)(l + q * 4096), 16, 0, 0);
}

template<int F0>
__device__ __forceinline__ void read_a4(s16x8 (&a)[8], const short* pA) {
    #pragma unroll
    for (int i = 0; i < 4; ++i)
        a[F0 + i] = *(const s16x8*)(pA + (F0 + i) * 512);
}

__device__ __forceinline__ void read_b4(s16x8 (&b)[4], const short* pB) {
    #pragma unroll
    for (int n = 0; n < 4; ++n)
        b[n] = *(const s16x8*)(pB + n * 512);
}

template<int N>
__device__ __forceinline__ void read_b1(s16x8 (&b)[4], const short* pB) {
    b[N] = *(const s16x8*)(pB + N * 512);
}

// 16 independent MFMAs: frags F0..F0+3 x b[0..3], one MFMA per acc cell
template<int F0>
__device__ __forceinline__ void mfma_half(f32x4 (&acc)[8][4], s16x8 (&a)[8],
                                          s16x8 (&b)[4]) {
    #pragma unroll
    for (int f = 0; f < 4; ++f)
        #pragma unroll
        for (int n = 0; n < 4; ++n)
            acc[F0 + f][n] = __builtin_amdgcn_mfma_f32_16x16x32_bf16(
                a[F0 + f], b[n], acc[F0 + f][n], 0, 0, 0);
}

// column group of half2: frags 4..7 x b[N]
template<int N>
__device__ __forceinline__ void mfma_col(f32x4 (&acc)[8][4], s16x8 (&a)[8],
                                         s16x8 (&b)[4]) {
    #pragma unroll
    for (int f = 4; f < 8; ++f)
        acc[f][N] = __builtin_amdgcn_mfma_f32_16x16x32_bf16(
            a[f], b[N], acc[f][N], 0, 0, 0);
}

#define MEMCLOB asm volatile("" ::: "memory")
#define BAR     __builtin_amdgcn_s_barrier()
#define SCHED0  __builtin_amdgcn_sched_barrier(0)

#define ILV(N, PP) do {                                                       \
    mfma_col<N>(acc, a, b);                                                   \
    read_b1<N>(b, bB[(PP) ^ 1]); } while (0)

// One K-tile(32), parity P. Entry invariant: reads in flight = b(t)[4]+a0-3(t)[4]
// (oldest first); stages in flight = tile t+1's B(2)+A(2).
#define TILE_BODY(P) do {                                                     \
    const int t = 2 * t2 + (P);                                               \
    /* p1: issue a4-7(t); drain b+a0-3; BAR; stage B(t+2) into cur-B         */\
    /* (all waves' b(t) reads just drained); MFMA half1.                     */\
    read_a4<4>(a, bA[P]);                                                     \
    MEMCLOB;                                                                  \
    asm volatile("s_waitcnt lgkmcnt(4)" ::: "memory"); SCHED0;                \
    MEMCLOB; BAR;                                                             \
    if (t < NT32 - 2) stage2(gB + 64, sB[P]);                                 \
    __builtin_amdgcn_s_setprio(1);                                            \
    mfma_half<0>(acc, a, b);                                                  \
    __builtin_amdgcn_s_setprio(0);                                            \
    /* p2: drain a4-7; BAR; stage A(t+2); vmcnt proves t+1 staged; BAR       */\
    /* publishes; then {mfma-col n ; read b(t+1)[n]} interleave + a0-3(t+1). */\
    MEMCLOB;                                                                  \
    asm volatile("s_waitcnt lgkmcnt(0)" ::: "memory"); SCHED0;                \
    MEMCLOB; BAR;                                                             \
    if (t < NT32 - 2) stage2(gA + 64, sA[P]);                                 \
    if (t < NT32 - 2)       asm volatile("s_waitcnt vmcnt(4)" ::: "memory");  \
    else if (t == NT32 - 2) asm volatile("s_waitcnt vmcnt(0)" ::: "memory");  \
    MEMCLOB; BAR;                                                             \
    if (t + 1 < NT32) {                                                       \
        __builtin_amdgcn_s_setprio(1);                                        \
        ILV(0, P); ILV(1, P); ILV(2, P); ILV(3, P);                           \
        read_a4<0>(a, bA[(P) ^ 1]);                                           \
        __builtin_amdgcn_s_setprio(0);                                        \
    } else {                                                                  \
        __builtin_amdgcn_s_setprio(1);                                        \
        mfma_col<0>(acc, a, b); mfma_col<1>(acc, a, b);                       \
        mfma_col<2>(acc, a, b); mfma_col<3>(acc, a, b);                       \
        __builtin_amdgcn_s_setprio(0);                                        \
    }                                                                         \
    MEMCLOB;                                                                  \
    gA += 32; gB += 32;                                                       \
} while (0)

__global__ __launch_bounds__(512, 2)
void gemm32(const short* __restrict__ A, const short* __restrict__ B,
            float* __restrict__ C) {
    extern __shared__ short smem[];

    const int tid  = threadIdx.x;
    const int lane = tid & 63;
    const int wid  = tid >> 6;
    const int wm   = wid >> 2;      // 0..1  (128 rows each)
    const int wn   = wid & 3;       // 0..3  (64 cols each)
    const int r15  = lane & 15;
    const int kg   = lane >> 4;     // 0..3 (k-granule)
    const int l4   = lane >> 2;     // 0..15 (staging row within 16-row block)
    const int g4   = (lane & 3) ^ (l4 & 3);  // pre-swizzled source granule

    const int bid = blockIdx.x;
    const int sw  = (bid & 7) * 64 + (bid >> 3);   // bijective (512 % 8 == 0)
    const int bm  = sw >> 4;   // 0..31
    const int bn  = sw & 15;   // 0..15

    // per-lane staging sources; advance 32 shorts per K-tile.
    // instr q of stage2 adds q*128 rows (handled inside stage2).
    const short* gA = A + (size_t)(bm * 256 + wid * 16 + l4) * K_TOT + g4 * 8;
    const short* gB = B + (size_t)(bn * 256 + wid * 16 + l4) * K_TOT + g4 * 8;

    // staging dests (wave-uniform): rows [16*(wid+8q), +16)
    short* sA[2] = { smem + wid * 512, smem + 16384 + wid * 512 };
    short* sB[2] = { smem + 8192 + wid * 512, smem + 24576 + wid * 512 };

    // read bases: off(row) = row*32 + ((kg ^ (row&3))<<3); row = CONST16 + r15
    const int rbase = r15 * 32 + ((kg ^ (r15 & 3)) << 3);
    const short* bA[2] = { smem + wm * 4096 + rbase,
                           smem + 16384 + wm * 4096 + rbase };
    const short* bB[2] = { smem + 8192 + wn * 2048 + rbase,
                           smem + 24576 + wn * 2048 + rbase };

    // Prologue: stage tile0 + tile1 (8 instrs), wait tile0, BAR, lead reads.
    stage2(gB, sB[0]);
    stage2(gA, sA[0]);
    stage2(gB + 32, sB[1]);
    stage2(gA + 32, sA[1]);
    asm volatile("s_waitcnt vmcnt(4)" ::: "memory");
    MEMCLOB; BAR;

    f32x4 acc[8][4];
    #pragma unroll
    for (int f = 0; f < 8; ++f)
        #pragma unroll
        for (int n = 0; n < 4; ++n)
            acc[f][n] = (f32x4){0.f, 0.f, 0.f, 0.f};

    s16x8 a[8];
    s16x8 b[4];

    // lead reads for tile0: b then a0-3 (8 in flight)
    read_b4(b, bB[0]);
    read_a4<0>(a, bA[0]);

    for (int t2 = 0; t2 < NT32 / 2; ++t2) {
        TILE_BODY(0);
        TILE_BODY(1);
    }

    // Epilogue: 16x16 C/D layout col=lane&15, row=(lane>>4)*4+jj [m89-verified]
    // frag f row = bm*256 + wm*128 + f*16 + kg*4 + jj; col = bn*256 + wn*64 + n*16 + r15
    float* Cp = C + (size_t)(bm * 256 + wm * 128 + kg * 4) * N_TOT
                  + bn * 256 + wn * 64 + r15;
    #pragma unroll
    for (int f = 0; f < 8; ++f)
        #pragma unroll
        for (int n = 0; n < 4; ++n)
            #pragma unroll
            for (int jj = 0; jj < 4; ++jj)
                Cp[(size_t)(f * 16 + jj) * N_TOT + n * 16] = acc[f][n][jj];
}

// ---------------- fallback (only if ws too small) ----------------
#define PAD_ROW 40
__global__ __launch_bounds__(256, 2)
void gemm_rs_fused(const float* __restrict__ A, const float* __restrict__ B,
                   float* __restrict__ C) {
    __shared__ short lA[128 * PAD_ROW];
    __shared__ short lB[128 * PAD_ROW];
    const int bid = blockIdx.x;
    const int sw  = (bid & 7) * (int)(gridDim.x >> 3) + (bid >> 3);
    const int bm = sw >> 5, bn = sw & 31;
    const int tid = threadIdx.x, lane = tid & 63, wid = tid >> 6;
    const int wr = wid >> 1, wc = wid & 1, r15 = lane & 15, kg = lane >> 4;
    const int srow = tid >> 1, scg = tid & 1;
    const float* gA = A + ((size_t)(bm * 128 + srow) << 10) + scg * 16;
    const float* gB = B + ((size_t)(bn * 128 + srow) << 10) + scg * 16;
    short* wpA = lA + srow * PAD_ROW + scg * 16;
    short* wpB = lB + srow * PAD_ROW + scg * 16;
    const short* rpA = lA + (wr * 64 + r15) * PAD_ROW + kg * 8;
    const short* rpB = lB + (wc * 64 + r15) * PAD_ROW + kg * 8;
    f32x4 acc[4][4];
    #pragma unroll
    for (int i = 0; i < 4; ++i)
        #pragma unroll
        for (int j = 0; j < 4; ++j) acc[i][j] = (f32x4){0.f, 0.f, 0.f, 0.f};
    for (int t = 0; t < K_TOT / 32; ++t) {
        const int r = t >> 5, k0 = (t & 31) << 5;
        const float* pA = gA + (size_t)r * (M_TOT * LK) + k0;
        const float* pB = gB + (size_t)r * (N_TOT * LK) + k0;
        f32x4 va[4], vb[4];
        #pragma unroll
        for (int q = 0; q < 4; ++q) va[q] = *(const f32x4*)(pA + q * 4);
        #pragma unroll
        for (int q = 0; q < 4; ++q) vb[q] = *(const f32x4*)(pB + q * 4);
        __syncthreads();
        s16x8 oa0, oa1, ob0, ob1;
        #pragma unroll
        for (int q = 0; q < 2; ++q)
            #pragma unroll
            for (int i = 0; i < 4; ++i) {
                oa0[q * 4 + i] = f2bf(va[q][i]);
                oa1[q * 4 + i] = f2bf(va[q + 2][i]);
                ob0[q * 4 + i] = f2bf(vb[q][i]);
                ob1[q * 4 + i] = f2bf(vb[q + 2][i]);
            }
        *(s16x8*)(wpA) = oa0; *(s16x8*)(wpA + 8) = oa1;
        *(s16x8*)(wpB) = ob0; *(s16x8*)(wpB + 8) = ob1;
        __syncthreads();
        s16x8 af[4], bfr2[4];
        #pragma unroll
        for (int i = 0; i < 4; ++i) af[i]   = *(const s16x8*)(rpA + i * 16 * PAD_ROW);
        #pragma unroll
        for (int i = 0; i < 4; ++i) bfr2[i] = *(const s16x8*)(rpB + i * 16 * PAD_ROW);
        #pragma unroll
        for (int i = 0; i < 4; ++i)
            #pragma unroll
            for (int j = 0; j < 4; ++j)
                acc[i][j] = __builtin_amdgcn_mfma_f32_16x16x32_bf16(
                    af[i], bfr2[j], acc[i][j], 0, 0, 0);
    }
    float* Cp = C + (size_t)(bm * 128 + wr * 64 + kg * 4) * N_TOT
                  + bn * 128 + wc * 64 + r15;
    #pragma unroll
    for (int i = 0; i < 4; ++i)
        #pragma unroll
        for (int j = 0; j < 4; ++j)
            #pragma unroll
            for (int jj = 0; jj < 4; ++jj)
                Cp[(size_t)(i * 16 + jj) * N_TOT + j * 16] = acc[i][j][jj];
}

extern "C" void kernel_launch(void* const* d_in, const int* in_sizes, int n_in,
                              void* d_out, int out_size, void* d_ws, size_t ws_size,
                              hipStream_t stream) {
    const float* A = (const float*)d_in[0];   // [8, 8192, 1024]
    const float* B = (const float*)d_in[1];   // [8, 4096, 1024]
    float* C = (float*)d_out;                 // [8192, 4096]

    const size_t needA = (size_t)M_TOT * K_TOT * 2;
    const size_t needB = (size_t)N_TOT * K_TOT * 2;

    if (ws_size >= needA + needB) {
        short* Abf = (short*)d_ws;
        short* Bbf = (short*)((char*)d_ws + needA);
        cvt_all<<<dim3(NR * (M_TOT + N_TOT) / 2), dim3(256), 0, stream>>>(A, B, Abf, Bbf);
        gemm32<<<dim3((M_TOT / 256) * (N_TOT / 256)), dim3(512), 65536, stream>>>(Abf, Bbf, C);
    } else {
        gemm_rs_fused<<<dim3((M_TOT / 128) * (N_TOT / 128)), dim3(256), 0, stream>>>(A, B, C);
    }
}

// Round 12
// 562.806 us; speedup vs baseline: 1.0711x; 1.0711x over previous
//
#include <hip/hip_runtime.h>
#include <hip/hip_bf16.h>

// C[m,n] = sum_{r,k} A[r][m][k] * B[r][n][k]
// Phase 1: merged convert A,B -> bf16 in d_ws (K contiguous: k' = r*1024+k).
// Phase 2: 256x256 GEMM, BK=64, 32x32x16 MFMA, 8 waves (2Mx4N), r10 schedule.
// r11 lesson: occupancy is REGISTER-capped at 2 waves/SIMD (acc 128 AGPR);
// LDS-halving gave no TLP, only conflicts. This round: same skeleton, higher
// MFMA FLOP/cy (32x32x16: 4060 vs 3378 FLOP/cy/CU) with fragments held to
// 64 VGPR (r4's spill fixed). Cluster rows match r10's -> same race analysis.

#define M_TOT 8192
#define N_TOT 4096
#define LK    1024
#define NR    8
#define K_TOT (NR * LK)    // 8192
#define NT    (K_TOT / 64) // 128 K-tiles

typedef float f32x4  __attribute__((ext_vector_type(4)));
typedef float f32x16 __attribute__((ext_vector_type(16)));
typedef short s16x8  __attribute__((ext_vector_type(8)));
typedef const __attribute__((address_space(1))) unsigned int* gptr_t;
typedef __attribute__((address_space(3))) unsigned int* lptr_t;

__device__ inline short f2bf(float f) {
    __hip_bfloat16 h = __float2bfloat16(f);
    return *reinterpret_cast<short*>(&h);
}

// ---------------- merged convert pre-pass ----------------
__global__ __launch_bounds__(256)
void cvt_all(const float* __restrict__ A, const float* __restrict__ B,
             short* __restrict__ Abf, short* __restrict__ Bbf) {
    int bid = blockIdx.x;
    const float* in;
    short* out;
    int row_shift, row_mask;
    if (bid < 32768) { in = A; out = Abf; row_shift = 13; row_mask = 8191; }
    else { bid -= 32768; in = B; out = Bbf; row_shift = 12; row_mask = 4095; }
    const int row = bid * 2 + (threadIdx.x >> 7);
    const int c   = (threadIdx.x & 127) * 8;
    const int r   = row >> row_shift;
    const int m   = row & row_mask;
    const float* src = in + ((size_t)row << 10) + c;
    f32x4 v0 = *(const f32x4*)src;
    f32x4 v1 = *(const f32x4*)(src + 4);
    s16x8 o;
    #pragma unroll
    for (int j = 0; j < 4; ++j) { o[j] = f2bf(v0[j]); o[j + 4] = f2bf(v1[j]); }
    *(s16x8*)(out + ((size_t)m << 13) + ((size_t)r << 10) + c) = o;
}

// ---------------- GEMM ----------------
// LDS (shorts): A-par0 [0,16384), A-par1 [16384,32768),
//               B-par0 [32768,49152), B-par1 [49152,65536).  (128 KiB)
// A/B tiles [256][64]; granule g of row r holds global granule g^(r&7).
// Parity byte-stride 32768 -> all read offsets stay < 64 KiB ds-immediates.

template<int HALF, int D>
__device__ __forceinline__ void stage(const short* g, short* l) {
    #pragma unroll
    for (int q = 0; q < 2; ++q) {
        const short* src = g + (size_t)(HALF * 128 + q * 8) * K_TOT + D * 64;
        short* dst = l + (HALF * 128 + q * 8) * 64;
        __builtin_amdgcn_global_load_lds((gptr_t)src, (lptr_t)dst, 16, 0, 0);
    }
}

// A cluster MF (rows MF*64 + wm*32 + c31), afr slot MF&1, ks 0..3
template<int MF, int P>
__device__ __forceinline__ void read_a(s16x8 (&afr)[2][4], const short* const (&bA)[4]) {
    #pragma unroll
    for (int ks = 0; ks < 4; ++ks)
        afr[MF & 1][ks] = *(const s16x8*)(bA[ks] + MF * 4096 + P * 16384);
}

template<int P>
__device__ __forceinline__ void read_b_all(s16x8 (&bfr)[2][4], const short* const (&bB)[4]) {
    #pragma unroll
    for (int nf = 0; nf < 2; ++nf)
        #pragma unroll
        for (int ks = 0; ks < 4; ++ks)
            bfr[nf][ks] = *(const s16x8*)(bB[ks] + nf * 2048 + P * 16384);
}

// cluster MF: 2 nf x 4 ks, ks-outer/nf-inner so dependent MFMAs are 2 apart
template<int MF>
__device__ __forceinline__ void mfma_cluster(f32x16 (&acc)[4][2], s16x8 (&afr)[2][4],
                                             s16x8 (&bfr)[2][4]) {
    __builtin_amdgcn_s_setprio(1);
    #pragma unroll
    for (int ks = 0; ks < 4; ++ks)
        #pragma unroll
        for (int nf = 0; nf < 2; ++nf)
            acc[MF][nf] = __builtin_amdgcn_mfma_f32_32x32x16_bf16(
                afr[MF & 1][ks], bfr[nf][ks], acc[MF][nf], 0, 0, 0);
    __builtin_amdgcn_s_setprio(0);
}

// boundary interleave step S: 2 MFMAs of cluster3 at ks=S, then overwrite
// bfr[*][S] with next-tile B reads (program order resolves the WAR)
template<int S, int PN>
__device__ __forceinline__ void ilv_step(f32x16 (&acc)[4][2], s16x8 (&afr)[2][4],
                                         s16x8 (&bfr)[2][4], const short* const (&bB)[4]) {
    acc[3][0] = __builtin_amdgcn_mfma_f32_32x32x16_bf16(afr[1][S], bfr[0][S], acc[3][0], 0, 0, 0);
    acc[3][1] = __builtin_amdgcn_mfma_f32_32x32x16_bf16(afr[1][S], bfr[1][S], acc[3][1], 0, 0, 0);
    bfr[0][S] = *(const s16x8*)(bB[S] + PN * 16384);
    bfr[1][S] = *(const s16x8*)(bB[S] + 2048 + PN * 16384);
}

#define MEMCLOB asm volatile("" ::: "memory")
#define BAR     __builtin_amdgcn_s_barrier()
#define SCHED0  __builtin_amdgcn_sched_barrier(0)

// One K-tile, parity P. Entry invariant: reads in flight = B'(8)+c0'(4);
// stage instrs in flight handled by vmcnt(4) at p4 (counts identical to r10).
#define TILE_BODY(P) do {                                                     \
    const int t = 2 * t2 + (P);                                               \
    /* p1: issue c1; stage A1(t+1) -> next buffer */                          \
    read_a<1, P>(afr, bA);                                                    \
    if (t + 1 < NT) stage<1, 1>(gA, stA[(P) ^ 1]);                            \
    MEMCLOB; BAR;                                                             \
    asm volatile("s_waitcnt lgkmcnt(4)" ::: "memory"); SCHED0;                \
    mfma_cluster<0>(acc, afr, bfr);                                           \
    MEMCLOB; BAR;                                                             \
    /* p2: issue c2; stage B0(t+2) (B reads drained at p1 lgkm + BAR) */      \
    read_a<2, P>(afr, bA);                                                    \
    if (t + 2 < NT) stage<0, 2>(gB, stB[P]);                                  \
    MEMCLOB; BAR;                                                             \
    asm volatile("s_waitcnt lgkmcnt(4)" ::: "memory"); SCHED0;                \
    mfma_cluster<1>(acc, afr, bfr);                                           \
    MEMCLOB; BAR;                                                             \
    /* p3: issue c3; stage B1(t+2) */                                         \
    read_a<3, P>(afr, bA);                                                    \
    if (t + 2 < NT) stage<1, 2>(gB, stB[P]);                                  \
    MEMCLOB; BAR;                                                             \
    asm volatile("s_waitcnt lgkmcnt(4)" ::: "memory"); SCHED0;                \
    mfma_cluster<2>(acc, afr, bfr);                                           \
    MEMCLOB; BAR;                                                             \
    /* p4: vmcnt(4) proves t+1 staged; BAR publishes; stage A0(t+2)           */\
    /* (rows 0-127 = c0+c1, drained by p2); read c0'; drain c3;              */\
    /* interleave mfma-c3 with next-tile B reads.                            */\
    if (t < NT - 2)       asm volatile("s_waitcnt vmcnt(4)" ::: "memory");    \
    else if (t == NT - 2) asm volatile("s_waitcnt vmcnt(0)" ::: "memory");    \
    MEMCLOB; BAR;                                                             \
    if (t + 2 < NT) stage<0, 2>(gA, stA[P]);                                  \
    if (t + 1 < NT) {                                                         \
        read_a<0, (P) ^ 1>(afr, bA);                                          \
        asm volatile("s_waitcnt lgkmcnt(4)" ::: "memory"); SCHED0;            \
        __builtin_amdgcn_s_setprio(1);                                        \
        ilv_step<0, (P) ^ 1>(acc, afr, bfr, bB);                              \
        ilv_step<1, (P) ^ 1>(acc, afr, bfr, bB);                              \
        ilv_step<2, (P) ^ 1>(acc, afr, bfr, bB);                              \
        ilv_step<3, (P) ^ 1>(acc, afr, bfr, bB);                              \
        __builtin_amdgcn_s_setprio(0);                                        \
    } else {                                                                  \
        asm volatile("s_waitcnt lgkmcnt(0)" ::: "memory"); SCHED0;            \
        mfma_cluster<3>(acc, afr, bfr);                                       \
    }                                                                         \
    MEMCLOB; BAR;                                                             \
    gA += 64; gB += 64;                                                       \
} while (0)

__global__ __launch_bounds__(512, 2)
void gemm8(const short* __restrict__ A, const short* __restrict__ B,
           float* __restrict__ C) {
    extern __shared__ short smem[];

    const int tid  = threadIdx.x;
    const int lane = tid & 63;
    const int wid  = tid >> 6;
    const int wm   = wid >> 2;      // 0..1
    const int wn   = wid & 3;       // 0..3
    const int c31  = lane & 31;
    const int kh   = lane >> 5;     // 0..1
    const int l8   = lane >> 3;     // 0..7
    const int g16  = (lane & 7) ^ l8;  // pre-swizzled source granule (staging)

    const int bid = blockIdx.x;
    const int sw  = (bid & 7) * 64 + (bid >> 3);   // bijective (512 % 8 == 0)
    const int bm  = sw >> 4;   // 0..31
    const int bn  = sw & 15;   // 0..15

    // staging sources (advance 64 shorts per K-tile) — identical to r10
    const short* gA = A + (size_t)(bm * 256 + wid * 16 + l8) * K_TOT + g16 * 8;
    const short* gB = B + (size_t)(bn * 256 + wid * 16 + l8) * K_TOT + g16 * 8;

    // staging dests (wave-uniform), parity via array index
    short* stA[2] = { smem + wid * 1024, smem + 16384 + wid * 1024 };
    short* stB[2] = { smem + 32768 + wid * 1024, smem + 49152 + wid * 1024 };

    // ds_read bases per ks: granule gk = (ks*2+kh) ^ (c31&7)
    // A row base = wm*32 + c31 (cluster offset MF*64 rows via immediate)
    // B row base = wn*64 + c31 (nf*32 rows via immediate)
    const short* bA[4];
    const short* bB[4];
    #pragma unroll
    for (int ks = 0; ks < 4; ++ks) {
        const int gk = (ks * 2 + kh) ^ (c31 & 7);
        bA[ks] = smem + (wm * 32 + c31) * 64 + gk * 8;
        bB[ks] = smem + 32768 + (wn * 64 + c31) * 64 + gk * 8;
    }

    // Prologue: tile0 complete + tile1 {B0,B1,A0} = 14 load instrs.
    stage<0, 0>(gB, stB[0]);
    stage<1, 0>(gB, stB[0]);
    stage<0, 0>(gA, stA[0]);
    stage<1, 0>(gA, stA[0]);
    stage<0, 1>(gB, stB[1]);
    stage<1, 1>(gB, stB[1]);
    stage<0, 1>(gA, stA[1]);
    asm volatile("s_waitcnt vmcnt(6)" ::: "memory");  // tile0's 8 loads done
    MEMCLOB; BAR;

    f32x16 acc[4][2];
    #pragma unroll
    for (int f = 0; f < 4; ++f)
        #pragma unroll
        for (int n = 0; n < 2; ++n)
            #pragma unroll
            for (int e = 0; e < 16; ++e)
                acc[f][n][e] = 0.f;

    s16x8 afr[2][4];
    s16x8 bfr[2][4];

    // Pre-loop: tile0's B (8) + c0 (4) reads in flight
    read_b_all<0>(bfr, bB);
    read_a<0, 0>(afr, bA);

    for (int t2 = 0; t2 < NT / 2; ++t2) {
        TILE_BODY(0);
        TILE_BODY(1);
    }

    // Epilogue: 32x32 C/D layout col=lane&31, row=(reg&3)+8*(reg>>2)+4*kh
    // [m74/m101-verified; r4 hardware-verified end-to-end]
    float* Cp = C + (size_t)(bm * 256 + wm * 32 + 4 * kh) * N_TOT
                  + bn * 256 + wn * 64 + c31;
    #pragma unroll
    for (int mf = 0; mf < 4; ++mf)
        #pragma unroll
        for (int nf = 0; nf < 2; ++nf)
            #pragma unroll
            for (int reg = 0; reg < 16; ++reg) {
                const int roff = mf * 64 + (reg & 3) + 8 * (reg >> 2);
                Cp[(size_t)roff * N_TOT + nf * 32] = acc[mf][nf][reg];
            }
}

// ---------------- fallback (only if ws too small) ----------------
#define PAD_ROW 40
__global__ __launch_bounds__(256, 2)
void gemm_rs_fused(const float* __restrict__ A, const float* __restrict__ B,
                   float* __restrict__ C) {
    __shared__ short lA[128 * PAD_ROW];
    __shared__ short lB[128 * PAD_ROW];
    const int bid = blockIdx.x;
    const int sw  = (bid & 7) * (int)(gridDim.x >> 3) + (bid >> 3);
    const int bm = sw >> 5, bn = sw & 31;
    const int tid = threadIdx.x, lane = tid & 63, wid = tid >> 6;
    const int wr = wid >> 1, wc = wid & 1, r15 = lane & 15, kg = lane >> 4;
    const int srow = tid >> 1, scg = tid & 1;
    const float* gA = A + ((size_t)(bm * 128 + srow) << 10) + scg * 16;
    const float* gB = B + ((size_t)(bn * 128 + srow) << 10) + scg * 16;
    short* wpA = lA + srow * PAD_ROW + scg * 16;
    short* wpB = lB + srow * PAD_ROW + scg * 16;
    const short* rpA = lA + (wr * 64 + r15) * PAD_ROW + kg * 8;
    const short* rpB = lB + (wc * 64 + r15) * PAD_ROW + kg * 8;
    f32x4 acc[4][4];
    #pragma unroll
    for (int i = 0; i < 4; ++i)
        #pragma unroll
        for (int j = 0; j < 4; ++j) acc[i][j] = (f32x4){0.f, 0.f, 0.f, 0.f};
    for (int t = 0; t < K_TOT / 32; ++t) {
        const int r = t >> 5, k0 = (t & 31) << 5;
        const float* pA = gA + (size_t)r * (M_TOT * LK) + k0;
        const float* pB = gB + (size_t)r * (N_TOT * LK) + k0;
        f32x4 va[4], vb[4];
        #pragma unroll
        for (int q = 0; q < 4; ++q) va[q] = *(const f32x4*)(pA + q * 4);
        #pragma unroll
        for (int q = 0; q < 4; ++q) vb[q] = *(const f32x4*)(pB + q * 4);
        __syncthreads();
        s16x8 oa0, oa1, ob0, ob1;
        #pragma unroll
        for (int q = 0; q < 2; ++q)
            #pragma unroll
            for (int i = 0; i < 4; ++i) {
                oa0[q * 4 + i] = f2bf(va[q][i]);
                oa1[q * 4 + i] = f2bf(va[q + 2][i]);
                ob0[q * 4 + i] = f2bf(vb[q][i]);
                ob1[q * 4 + i] = f2bf(vb[q + 2][i]);
            }
        *(s16x8*)(wpA) = oa0; *(s16x8*)(wpA + 8) = oa1;
        *(s16x8*)(wpB) = ob0; *(s16x8*)(wpB + 8) = ob1;
        __syncthreads();
        s16x8 af[4], bfr2[4];
        #pragma unroll
        for (int i = 0; i < 4; ++i) af[i]   = *(const s16x8*)(rpA + i * 16 * PAD_ROW);
        #pragma unroll
        for (int i = 0; i < 4; ++i) bfr2[i] = *(const s16x8*)(rpB + i * 16 * PAD_ROW);
        #pragma unroll
        for (int i = 0; i < 4; ++i)
            #pragma unroll
            for (int j = 0; j < 4; ++j)
                acc[i][j] = __builtin_amdgcn_mfma_f32_16x16x32_bf16(
                    af[i], bfr2[j], acc[i][j], 0, 0, 0);
    }
    float* Cp = C + (size_t)(bm * 128 + wr * 64 + kg * 4) * N_TOT
                  + bn * 128 + wc * 64 + r15;
    #pragma unroll
    for (int i = 0; i < 4; ++i)
        #pragma unroll
        for (int j = 0; j < 4; ++j)
            #pragma unroll
            for (int jj = 0; jj < 4; ++jj)
                Cp[(size_t)(i * 16 + jj) * N_TOT + j * 16] = acc[i][j][jj];
}

extern "C" void kernel_launch(void* const* d_in, const int* in_sizes, int n_in,
                              void* d_out, int out_size, void* d_ws, size_t ws_size,
                              hipStream_t stream) {
    const float* A = (const float*)d_in[0];   // [8, 8192, 1024]
    const float* B = (const float*)d_in[1];   // [8, 4096, 1024]
    float* C = (float*)d_out;                 // [8192, 4096]

    const size_t needA = (size_t)M_TOT * K_TOT * 2;
    const size_t needB = (size_t)N_TOT * K_TOT * 2;

    if (ws_size >= needA + needB) {
        short* Abf = (short*)d_ws;
        short* Bbf = (short*)((char*)d_ws + needA);
        cvt_all<<<dim3(NR * (M_TOT + N_TOT) / 2), dim3(256), 0, stream>>>(A, B, Abf, Bbf);
        gemm8<<<dim3((M_TOT / 256) * (N_TOT / 256)), dim3(512), 131072, stream>>>(Abf, Bbf, C);
    } else {
        gemm_rs_fused<<<dim3((M_TOT / 128) * (N_TOT / 128)), dim3(256), 0, stream>>>(A, B, C);
    }
}

// Round 13
// 518.671 us; speedup vs baseline: 1.1623x; 1.0851x over previous
//
#include <hip/hip_runtime.h>
#include <hip/hip_bf16.h>

// C[m,n] = sum_{r,k} A[r][m][k] * B[r][n][k]
// Phase 1: merged convert A,B -> bf16 in d_ws (K contiguous: k' = r*1024+k).
// Phase 2: r10 GEMM (best: 430us) with MINIMAL FENCING:
//          r12 lesson: 32x32 MFMA re-creates bank conflicts; r10's 16-row
//          pattern is the conflict-free one. This round removes the ~12
//          standalone memory-clobber fences per tile (kept: "memory" on all
//          waitcnt asms + sched_barrier(0) after each, rule #18) so the
//          compiler can hoist ds_reads/stages into MFMA shadows.

#define M_TOT 8192
#define N_TOT 4096
#define LK    1024
#define NR    8
#define K_TOT (NR * LK)    // 8192
#define NT    (K_TOT / 64) // 128 K-tiles

typedef float f32x4 __attribute__((ext_vector_type(4)));
typedef short s16x8 __attribute__((ext_vector_type(8)));
typedef const __attribute__((address_space(1))) unsigned int* gptr_t;
typedef __attribute__((address_space(3))) unsigned int* lptr_t;

__device__ inline short f2bf(float f) {
    __hip_bfloat16 h = __float2bfloat16(f);
    return *reinterpret_cast<short*>(&h);
}

// ---------------- merged convert pre-pass ----------------
__global__ __launch_bounds__(256)
void cvt_all(const float* __restrict__ A, const float* __restrict__ B,
             short* __restrict__ Abf, short* __restrict__ Bbf) {
    int bid = blockIdx.x;
    const float* in;
    short* out;
    int row_shift, row_mask;
    if (bid < 32768) { in = A; out = Abf; row_shift = 13; row_mask = 8191; }
    else { bid -= 32768; in = B; out = Bbf; row_shift = 12; row_mask = 4095; }
    const int row = bid * 2 + (threadIdx.x >> 7);
    const int c   = (threadIdx.x & 127) * 8;
    const int r   = row >> row_shift;
    const int m   = row & row_mask;
    const float* src = in + ((size_t)row << 10) + c;
    f32x4 v0 = *(const f32x4*)src;
    f32x4 v1 = *(const f32x4*)(src + 4);
    s16x8 o;
    #pragma unroll
    for (int j = 0; j < 4; ++j) { o[j] = f2bf(v0[j]); o[j + 4] = f2bf(v1[j]); }
    *(s16x8*)(out + ((size_t)m << 13) + ((size_t)r << 10) + c) = o;
}

// ---------------- GEMM ----------------
// LDS: buf P at P*32768 shorts; A-tile [256][64] at +0, B-tile at +16384.
// Swizzle: LDS granule g of row r holds global granule g ^ (r&7).

template<int HALF, int D>
__device__ __forceinline__ void stage(const short* g, short* l) {
    #pragma unroll
    for (int q = 0; q < 2; ++q) {
        const short* src = g + (size_t)(HALF * 128 + q * 8) * K_TOT + D * 64;
        short* dst = l + (HALF * 128 + q * 8) * 64;
        __builtin_amdgcn_global_load_lds((gptr_t)src, (lptr_t)dst, 16, 0, 0);
    }
}

// A cluster C: afr slot C&1; reads = base(ks) + const-offset (C*64+fo*16)*64
template<int C>
__device__ __forceinline__ void read_a(s16x8 (&afr)[2][2][2],
                                       const short* bA0, const short* bA1) {
    #pragma unroll
    for (int fo = 0; fo < 2; ++fo)
        #pragma unroll
        for (int ks = 0; ks < 2; ++ks)
            afr[C & 1][fo][ks] =
                *(const s16x8*)((ks ? bA1 : bA0) + (C * 64 + fo * 16) * 64);
}

__device__ __forceinline__ void read_b(s16x8 (&bfr)[4][2],
                                       const short* bB0, const short* bB1) {
    #pragma unroll
    for (int n = 0; n < 4; ++n)
        #pragma unroll
        for (int ks = 0; ks < 2; ++ks)
            bfr[n][ks] = *(const s16x8*)((ks ? bB1 : bB0) + n * 1024);
}

template<int N>
__device__ __forceinline__ void read_b_one(s16x8 (&bfr)[4][2],
                                           const short* bB0, const short* bB1) {
    #pragma unroll
    for (int ks = 0; ks < 2; ++ks)
        bfr[N][ks] = *(const s16x8*)((ks ? bB1 : bB0) + N * 1024);
}

template<int Q>
__device__ __forceinline__ void mfma_quad(f32x4 (&acc)[8][4], s16x8 (&afr)[2][2][2],
                                          s16x8 (&bfr)[4][2]) {
    __builtin_amdgcn_s_setprio(1);
    #pragma unroll
    for (int fo = 0; fo < 2; ++fo)
        #pragma unroll
        for (int n = 0; n < 4; ++n)
            #pragma unroll
            for (int ks = 0; ks < 2; ++ks)
                acc[Q * 2 + fo][n] = __builtin_amdgcn_mfma_f32_16x16x32_bf16(
                    afr[Q & 1][fo][ks], bfr[n][ks], acc[Q * 2 + fo][n], 0, 0, 0);
    __builtin_amdgcn_s_setprio(0);
}

template<int N>
__device__ __forceinline__ void mfma_n3(f32x4 (&acc)[8][4], s16x8 (&afr)[2][2][2],
                                        s16x8 (&bfr)[4][2]) {
    #pragma unroll
    for (int fo = 0; fo < 2; ++fo)
        #pragma unroll
        for (int ks = 0; ks < 2; ++ks)
            acc[6 + fo][N] = __builtin_amdgcn_mfma_f32_16x16x32_bf16(
                afr[1][fo][ks], bfr[N][ks], acc[6 + fo][N], 0, 0, 0);
}

#define BAR     __builtin_amdgcn_s_barrier()
#define SCHED0  __builtin_amdgcn_sched_barrier(0)

#define INTERLEAVE_STEP(N, PP) do {                                           \
    mfma_n3<N>(acc, afr, bfr);                                                \
    read_b_one<N>(bfr, bB0[(PP) ^ 1], bB1[(PP) ^ 1]); } while (0)

// One K-tile, parity P. Schedule = r10; fencing minimal (waitcnt asms carry
// the only memory clobbers; barriers are plain).
#define TILE_BODY(P) do {                                                     \
    const int t = 2 * t2 + (P);                                               \
    /* p1: issue c1; stage A1(t+1) */                                         \
    read_a<1>(afr, bA0[P], bA1[P]);                                           \
    if (t + 1 < NT) stage<1, 1>(gA, stA[(P) ^ 1]);                            \
    BAR;                                                                      \
    asm volatile("s_waitcnt lgkmcnt(4)" ::: "memory"); SCHED0;                \
    mfma_quad<0>(acc, afr, bfr);                                              \
    BAR;                                                                      \
    /* p2: issue c2; stage B0(t+2) */                                         \
    read_a<2>(afr, bA0[P], bA1[P]);                                           \
    if (t + 2 < NT) stage<0, 2>(gB, stB[P]);                                  \
    BAR;                                                                      \
    asm volatile("s_waitcnt lgkmcnt(4)" ::: "memory"); SCHED0;                \
    mfma_quad<1>(acc, afr, bfr);                                              \
    BAR;                                                                      \
    /* p3: issue c3; stage B1(t+2) */                                         \
    read_a<3>(afr, bA0[P], bA1[P]);                                           \
    if (t + 2 < NT) stage<1, 2>(gB, stB[P]);                                  \
    BAR;                                                                      \
    asm volatile("s_waitcnt lgkmcnt(4)" ::: "memory"); SCHED0;                \
    mfma_quad<2>(acc, afr, bfr);                                              \
    BAR;                                                                      \
    /* p4: counted vmcnt proves t+1 staged; stage A0(t+2); read c0';         */\
    /* drain c3; {mfma-group ; read bfr'} interleave.                        */\
    if (t < NT - 2)       asm volatile("s_waitcnt vmcnt(4)" ::: "memory");    \
    else if (t == NT - 2) asm volatile("s_waitcnt vmcnt(0)" ::: "memory");    \
    BAR;                                                                      \
    if (t + 2 < NT) stage<0, 2>(gA, stA[P]);                                  \
    if (t + 1 < NT) {                                                         \
        read_a<0>(afr, bA0[(P) ^ 1], bA1[(P) ^ 1]);                           \
        asm volatile("s_waitcnt lgkmcnt(4)" ::: "memory"); SCHED0;            \
        __builtin_amdgcn_s_setprio(1);                                        \
        INTERLEAVE_STEP(0, P); INTERLEAVE_STEP(1, P);                         \
        INTERLEAVE_STEP(2, P); INTERLEAVE_STEP(3, P);                         \
        __builtin_amdgcn_s_setprio(0);                                        \
    } else {                                                                  \
        asm volatile("s_waitcnt lgkmcnt(0)" ::: "memory"); SCHED0;            \
        __builtin_amdgcn_s_setprio(1);                                        \
        mfma_n3<0>(acc, afr, bfr); mfma_n3<1>(acc, afr, bfr);                 \
        mfma_n3<2>(acc, afr, bfr); mfma_n3<3>(acc, afr, bfr);                 \
        __builtin_amdgcn_s_setprio(0);                                        \
    }                                                                         \
    BAR;                                                                      \
    gA += 64; gB += 64;                                                       \
} while (0)

__global__ __launch_bounds__(512, 2)
void gemm8(const short* __restrict__ A, const short* __restrict__ B,
           float* __restrict__ C) {
    extern __shared__ short smem[];

    const int tid  = threadIdx.x;
    const int lane = tid & 63;
    const int wid  = tid >> 6;
    const int wm   = wid >> 2;      // 0..1
    const int wn   = wid & 3;       // 0..3
    const int r15  = lane & 15;
    const int kg   = lane >> 4;     // 0..3
    const int l8   = lane >> 3;     // 0..7
    const int g16  = (lane & 7) ^ l8;  // pre-swizzled source granule
    const int r7   = r15 & 7;

    const int bid = blockIdx.x;
    const int sw  = (bid & 7) * 64 + (bid >> 3);   // bijective (512 % 8 == 0)
    const int bm  = sw >> 4;   // 0..31
    const int bn  = sw & 15;   // 0..15

    // running per-lane staging sources (advance by 64 shorts per K-tile)
    const short* gA = A + (size_t)(bm * 256 + wid * 16 + l8) * K_TOT + g16 * 8;
    const short* gB = B + (size_t)(bn * 256 + wid * 16 + l8) * K_TOT + g16 * 8;

    // per-parity wave-uniform staging dests (include wid*16 rows)
    short* stA[2] = { smem + wid * 1024, smem + 32768 + wid * 1024 };
    short* stB[2] = { smem + 16384 + wid * 1024, smem + 49152 + wid * 1024 };

    // per-parity ds_read bases: off(row,ks) = row*64 + (((ks<<2|kg)^(row&7))<<3)
    const int gk0 = kg ^ r7;            // ks=0 granule
    const int gk1 = (4 | kg) ^ r7;      // ks=1 granule
    const short* bA0[2], *bA1[2], *bB0[2], *bB1[2];
    #pragma unroll
    for (int p = 0; p < 2; ++p) {
        const short* base = smem + p * 32768;
        bA0[p] = base + (wm * 32 + r15) * 64 + gk0 * 8;
        bA1[p] = base + (wm * 32 + r15) * 64 + gk1 * 8;
        bB0[p] = base + 16384 + (wn * 64 + r15) * 64 + gk0 * 8;
        bB1[p] = base + 16384 + (wn * 64 + r15) * 64 + gk1 * 8;
    }

    // Prologue: tile0 complete + tile1 {B0,B1,A0} = 14 load instrs.
    stage<0, 0>(gB, stB[0]);
    stage<1, 0>(gB, stB[0]);
    stage<0, 0>(gA, stA[0]);
    stage<1, 0>(gA, stA[0]);
    stage<0, 1>(gB, stB[1]);
    stage<1, 1>(gB, stB[1]);
    stage<0, 1>(gA, stA[1]);
    asm volatile("s_waitcnt vmcnt(6)" ::: "memory");  // tile0's 8 loads done
    BAR;

    f32x4 acc[8][4];
    #pragma unroll
    for (int f = 0; f < 8; ++f)
        #pragma unroll
        for (int n = 0; n < 4; ++n)
            acc[f][n] = (f32x4){0.f, 0.f, 0.f, 0.f};

    s16x8 afr[2][2][2];
    s16x8 bfr[4][2];

    // Pre-loop: tile0's B + c0 reads in flight (12 ds_reads)
    read_b(bfr, bB0[0], bB1[0]);
    read_a<0>(afr, bA0[0], bA1[0]);

    for (int t2 = 0; t2 < NT / 2; ++t2) {
        TILE_BODY(0);
        TILE_BODY(1);
    }

    // Epilogue: 16x16 C/D layout col=lane&15, row=(lane>>4)*4+jj [m89-verified]
    float* Cp = C + (size_t)(bm * 256 + wm * 32 + kg * 4) * N_TOT
                  + bn * 256 + wn * 64 + r15;
    #pragma unroll
    for (int f = 0; f < 8; ++f)
        #pragma unroll
        for (int n = 0; n < 4; ++n)
            #pragma unroll
            for (int jj = 0; jj < 4; ++jj) {
                const int roff = (f >> 1) * 64 + (f & 1) * 16 + jj;
                Cp[(size_t)roff * N_TOT + n * 16] = acc[f][n][jj];
            }
}

// ---------------- fallback (only if ws too small) ----------------
#define PAD_ROW 40
__global__ __launch_bounds__(256, 2)
void gemm_rs_fused(const float* __restrict__ A, const float* __restrict__ B,
                   float* __restrict__ C) {
    __shared__ short lA[128 * PAD_ROW];
    __shared__ short lB[128 * PAD_ROW];
    const int bid = blockIdx.x;
    const int sw  = (bid & 7) * (int)(gridDim.x >> 3) + (bid >> 3);
    const int bm = sw >> 5, bn = sw & 31;
    const int tid = threadIdx.x, lane = tid & 63, wid = tid >> 6;
    const int wr = wid >> 1, wc = wid & 1, r15 = lane & 15, kg = lane >> 4;
    const int srow = tid >> 1, scg = tid & 1;
    const float* gA = A + ((size_t)(bm * 128 + srow) << 10) + scg * 16;
    const float* gB = B + ((size_t)(bn * 128 + srow) << 10) + scg * 16;
    short* wpA = lA + srow * PAD_ROW + scg * 16;
    short* wpB = lB + srow * PAD_ROW + scg * 16;
    const short* rpA = lA + (wr * 64 + r15) * PAD_ROW + kg * 8;
    const short* rpB = lB + (wc * 64 + r15) * PAD_ROW + kg * 8;
    f32x4 acc[4][4];
    #pragma unroll
    for (int i = 0; i < 4; ++i)
        #pragma unroll
        for (int j = 0; j < 4; ++j) acc[i][j] = (f32x4){0.f, 0.f, 0.f, 0.f};
    for (int t = 0; t < K_TOT / 32; ++t) {
        const int r = t >> 5, k0 = (t & 31) << 5;
        const float* pA = gA + (size_t)r * (M_TOT * LK) + k0;
        const float* pB = gB + (size_t)r * (N_TOT * LK) + k0;
        f32x4 va[4], vb[4];
        #pragma unroll
        for (int q = 0; q < 4; ++q) va[q] = *(const f32x4*)(pA + q * 4);
        #pragma unroll
        for (int q = 0; q < 4; ++q) vb[q] = *(const f32x4*)(pB + q * 4);
        __syncthreads();
        s16x8 oa0, oa1, ob0, ob1;
        #pragma unroll
        for (int q = 0; q < 2; ++q)
            #pragma unroll
            for (int i = 0; i < 4; ++i) {
                oa0[q * 4 + i] = f2bf(va[q][i]);
                oa1[q * 4 + i] = f2bf(va[q + 2][i]);
                ob0[q * 4 + i] = f2bf(vb[q][i]);
                ob1[q * 4 + i] = f2bf(vb[q + 2][i]);
            }
        *(s16x8*)(wpA) = oa0; *(s16x8*)(wpA + 8) = oa1;
        *(s16x8*)(wpB) = ob0; *(s16x8*)(wpB + 8) = ob1;
        __syncthreads();
        s16x8 af[4], bfr2[4];
        #pragma unroll
        for (int i = 0; i < 4; ++i) af[i]   = *(const s16x8*)(rpA + i * 16 * PAD_ROW);
        #pragma unroll
        for (int i = 0; i < 4; ++i) bfr2[i] = *(const s16x8*)(rpB + i * 16 * PAD_ROW);
        #pragma unroll
        for (int i = 0; i < 4; ++i)
            #pragma unroll
            for (int j = 0; j < 4; ++j)
                acc[i][j] = __builtin_amdgcn_mfma_f32_16x16x32_bf16(
                    af[i], bfr2[j], acc[i][j], 0, 0, 0);
    }
    float* Cp = C + (size_t)(bm * 128 + wr * 64 + kg * 4) * N_TOT
                  + bn * 128 + wc * 64 + r15;
    #pragma unroll
    for (int i = 0; i < 4; ++i)
        #pragma unroll
        for (int j = 0; j < 4; ++j)
            #pragma unroll
            for (int jj = 0; jj < 4; ++jj)
                Cp[(size_t)(i * 16 + jj) * N_TOT + j * 16] = acc[i][j][jj];
}

extern "C" void kernel_launch(void* const* d_in, const int* in_sizes, int n_in,
                              void* d_out, int out_size, void* d_ws, size_t ws_size,
                              hipStream_t stream) {
    const float* A = (const float*)d_in[0];   // [8, 8192, 1024]
    const float* B = (const float*)d_in[1];   // [8, 4096, 1024]
    float* C = (float*)d_out;                 // [8192, 4096]

    const size_t needA = (size_t)M_TOT * K_TOT * 2;
    const size_t needB = (size_t)N_TOT * K_TOT * 2;

    if (ws_size >= needA + needB) {
        short* Abf = (short*)d_ws;
        short* Bbf = (short*)((char*)d_ws + needA);
        cvt_all<<<dim3(NR * (M_TOT + N_TOT) / 2), dim3(256), 0, stream>>>(A, B, Abf, Bbf);
        gemm8<<<dim3((M_TOT / 256) * (N_TOT / 256)), dim3(512), 131072, stream>>>(Abf, Bbf, C);
    } else {
        gemm_rs_fused<<<dim3((M_TOT / 128) * (N_TOT / 128)), dim3(256), 0, stream>>>(A, B, C);
    }
}